// Round 2
// baseline (3681.536 us; speedup 1.0000x reference)
//
#include <hip/hip_runtime.h>

// ---------------- CSR build ----------------

__global__ void k_deg(const int* __restrict__ dst, int* __restrict__ deg, int E) {
    int e = blockIdx.x * blockDim.x + threadIdx.x;
    if (e < E) atomicAdd(&deg[dst[e]], 1);
}

__global__ void k_scan1(const int* __restrict__ deg, int* __restrict__ partial,
                        int* __restrict__ blockSums, int n) {
    __shared__ int sh[256];
    int i = blockIdx.x * 256 + threadIdx.x;
    int v = (i < n) ? deg[i] : 0;
    sh[threadIdx.x] = v;
    __syncthreads();
    for (int off = 1; off < 256; off <<= 1) {
        int t = (threadIdx.x >= (unsigned)off) ? sh[threadIdx.x - off] : 0;
        __syncthreads();
        sh[threadIdx.x] += t;
        __syncthreads();
    }
    if (i < n) partial[i] = sh[threadIdx.x] - v;
    if (threadIdx.x == 255) blockSums[blockIdx.x] = sh[255];
}

__global__ void k_scan2(int* __restrict__ bs, int nb) {
    __shared__ int sh[512];
    int t = threadIdx.x;
    int v = (t < nb) ? bs[t] : 0;
    sh[t] = v;
    __syncthreads();
    for (int off = 1; off < 512; off <<= 1) {
        int u = (t >= off) ? sh[t - off] : 0;
        __syncthreads();
        sh[t] += u;
        __syncthreads();
    }
    if (t < nb) bs[t] = sh[t] - v;
}

__global__ void k_scan3(const int* __restrict__ partial, const int* __restrict__ bs,
                        int* __restrict__ start, int* __restrict__ cursor, int n) {
    int i = blockIdx.x * 256 + threadIdx.x;
    if (i < n) {
        int s = partial[i] + bs[blockIdx.x];
        start[i] = s;
        cursor[i] = s;
    }
}

__global__ void k_scatter(const int* __restrict__ src, const int* __restrict__ dst,
                          int* __restrict__ cursor, int* __restrict__ csr, int E) {
    int e = blockIdx.x * blockDim.x + threadIdx.x;
    if (e < E) {
        int d = dst[e];
        int p = atomicAdd(&cursor[d], 1);
        csr[p] = src[e];
    }
}

// ---------------- aggregation ----------------

// mean over 128-wide rows; one wave per node; float2/lane; unroll-4 for MLP.
__global__ void agg_l1(const float* __restrict__ feat, const int* __restrict__ csr,
                       const int* __restrict__ start, const int* __restrict__ deg,
                       float* __restrict__ agg, int n) {
    int gid = blockIdx.x * blockDim.x + threadIdx.x;
    int node = gid >> 6, lane = gid & 63;
    if (node >= n) return;
    int s = start[node], d = deg[node];
    const float2* f2 = (const float2*)feat;
    float2 a0 = {0.f, 0.f}, a1 = {0.f, 0.f}, a2 = {0.f, 0.f}, a3 = {0.f, 0.f};
    int j = 0;
    for (; j + 4 <= d; j += 4) {
        int i0 = csr[s + j], i1 = csr[s + j + 1], i2 = csr[s + j + 2], i3 = csr[s + j + 3];
        float2 v0 = f2[(size_t)i0 * 64 + lane];
        float2 v1 = f2[(size_t)i1 * 64 + lane];
        float2 v2 = f2[(size_t)i2 * 64 + lane];
        float2 v3 = f2[(size_t)i3 * 64 + lane];
        a0.x += v0.x; a0.y += v0.y;
        a1.x += v1.x; a1.y += v1.y;
        a2.x += v2.x; a2.y += v2.y;
        a3.x += v3.x; a3.y += v3.y;
    }
    for (; j < d; ++j) {
        float2 v = f2[(size_t)csr[s + j] * 64 + lane];
        a0.x += v.x; a0.y += v.y;
    }
    float inv = 1.0f / (float)max(d, 1);
    float2 r;
    r.x = ((a0.x + a1.x) + (a2.x + a3.x)) * inv;
    r.y = ((a0.y + a1.y) + (a2.y + a3.y)) * inv;
    ((float2*)agg)[(size_t)node * 64 + lane] = r;
}

// mean over 64-wide rows of p, ADD into out (out already holds z = h@Wr2 + b2).
__global__ void agg_l2(const float* __restrict__ p, const int* __restrict__ csr,
                       const int* __restrict__ start, const int* __restrict__ deg,
                       float* __restrict__ out, int n) {
    int gid = blockIdx.x * blockDim.x + threadIdx.x;
    int node = gid >> 6, lane = gid & 63;
    if (node >= n) return;
    int s = start[node], d = deg[node];
    float a0 = 0.f, a1 = 0.f, a2 = 0.f, a3 = 0.f;
    int j = 0;
    for (; j + 4 <= d; j += 4) {
        int i0 = csr[s + j], i1 = csr[s + j + 1], i2 = csr[s + j + 2], i3 = csr[s + j + 3];
        a0 += p[(size_t)i0 * 64 + lane];
        a1 += p[(size_t)i1 * 64 + lane];
        a2 += p[(size_t)i2 * 64 + lane];
        a3 += p[(size_t)i3 * 64 + lane];
    }
    for (; j < d; ++j) a0 += p[(size_t)csr[s + j] * 64 + lane];
    float m = (a0 + a1) + (a2 + a3);
    size_t o = (size_t)node * 64 + lane;
    out[o] = out[o] + m / (float)max(d, 1);
}

// ---------------- layer-1 dual GEMM: h = relu(A@Wl + B@Wr + b), K=128, FOUT=128 ----
// 1024 threads; tile = 128 nodes x 128 cols; thread = (ln, cg): 2 nodes x 8 cols.
// LDS: W chunk [16][128] x2 + transposed A/B [16][130] x2 = 33 KB.

__global__ __launch_bounds__(1024) void gemm_l1(
    const float* __restrict__ A, const float* __restrict__ B,
    const float* __restrict__ Wl, const float* __restrict__ Wr,
    const float* __restrict__ bias, float* __restrict__ out, int n, int ntiles) {
    __shared__ float sWl[16][128];
    __shared__ float sWr[16][128];
    __shared__ float sA[16][130];
    __shared__ float sB[16][130];
    int t = threadIdx.x;
    int ln = t & 63;     // node slot: nodes ln, ln+64
    int cg = t >> 6;     // 0..15, cols [cg*8, cg*8+8)
    float bs[8];
#pragma unroll
    for (int j = 0; j < 8; ++j) bs[j] = bias[cg * 8 + j];

    int half = t >> 9;           // 0: stage A+Wl, 1: stage B+Wr
    int sidx = t & 511;
    int snd = sidx >> 2, sc4 = sidx & 3;

    for (int tile = blockIdx.x; tile < ntiles; tile += gridDim.x) {
        int node0 = tile * 128;
        float acc0[8], acc1[8];
#pragma unroll
        for (int j = 0; j < 8; ++j) { acc0[j] = 0.f; acc1[j] = 0.f; }

        for (int kc = 0; kc < 128; kc += 16) {
            {
                int gn = min(node0 + snd, n - 1);
                const float* src = half ? B : A;
                float4 v = *(const float4*)&src[(size_t)gn * 128 + kc + sc4 * 4];
                float(*sT)[130] = half ? sB : sA;
                sT[sc4 * 4 + 0][snd] = v.x;
                sT[sc4 * 4 + 1][snd] = v.y;
                sT[sc4 * 4 + 2][snd] = v.z;
                sT[sc4 * 4 + 3][snd] = v.w;
                const float4* wsrc = (const float4*)((half ? Wr : Wl) + (size_t)kc * 128);
                float4* wdst = (float4*)(half ? &sWr[0][0] : &sWl[0][0]);
                wdst[sidx] = wsrc[sidx];
            }
            __syncthreads();
#pragma unroll
            for (int k = 0; k < 16; ++k) {
                float wlv[8], wrv[8];
                *(float4*)&wlv[0] = *(const float4*)&sWl[k][cg * 8];
                *(float4*)&wlv[4] = *(const float4*)&sWl[k][cg * 8 + 4];
                *(float4*)&wrv[0] = *(const float4*)&sWr[k][cg * 8];
                *(float4*)&wrv[4] = *(const float4*)&sWr[k][cg * 8 + 4];
                float a0 = sA[k][ln], a1 = sA[k][ln + 64];
                float b0 = sB[k][ln], b1 = sB[k][ln + 64];
#pragma unroll
                for (int j = 0; j < 8; ++j) {
                    acc0[j] += a0 * wlv[j] + b0 * wrv[j];
                    acc1[j] += a1 * wlv[j] + b1 * wrv[j];
                }
            }
            __syncthreads();
        }
        int n0 = node0 + ln, n1 = node0 + ln + 64;
        if (n0 < n) {
            float4 v0, v1;
            float* p0 = &v0.x; float* p1 = &v1.x;
#pragma unroll
            for (int j = 0; j < 4; ++j) {
                p0[j] = fmaxf(acc0[j] + bs[j], 0.f);
                p1[j] = fmaxf(acc0[j + 4] + bs[j + 4], 0.f);
            }
            *(float4*)&out[(size_t)n0 * 128 + cg * 8] = v0;
            *(float4*)&out[(size_t)n0 * 128 + cg * 8 + 4] = v1;
        }
        if (n1 < n) {
            float4 v0, v1;
            float* p0 = &v0.x; float* p1 = &v1.x;
#pragma unroll
            for (int j = 0; j < 4; ++j) {
                p0[j] = fmaxf(acc1[j] + bs[j], 0.f);
                p1[j] = fmaxf(acc1[j + 4] + bs[j + 4], 0.f);
            }
            *(float4*)&out[(size_t)n1 * 128 + cg * 8] = v0;
            *(float4*)&out[(size_t)n1 * 128 + cg * 8 + 4] = v1;
        }
    }
}

// ---------------- layer-2 dual-output GEMM: p = H@Wl, z(=out) = H@Wr + b --------
// 1024 threads; tile = 256 nodes x 64 cols; thread = (ln, cg): 2 nodes x 8 cols.
// LDS: W chunk [16][64] x2 + transposed A [16][260] = 25 KB.

__global__ __launch_bounds__(1024) void gemm_l2(
    const float* __restrict__ H, const float* __restrict__ Wl,
    const float* __restrict__ Wr, const float* __restrict__ bias,
    float* __restrict__ p, float* __restrict__ z, int n, int ntiles) {
    __shared__ float sWl[16][64];
    __shared__ float sWr[16][64];
    __shared__ float sA[16][260];
    int t = threadIdx.x;
    int ln = t & 127;    // node slot: nodes ln, ln+128
    int cg = t >> 7;     // 0..7
    float bs[8];
#pragma unroll
    for (int j = 0; j < 8; ++j) bs[j] = bias[cg * 8 + j];

    int snd = t >> 2, sc4 = t & 3;

    for (int tile = blockIdx.x; tile < ntiles; tile += gridDim.x) {
        int node0 = tile * 256;
        float accp0[8], accp1[8], accz0[8], accz1[8];
#pragma unroll
        for (int j = 0; j < 8; ++j) { accp0[j] = 0.f; accp1[j] = 0.f; accz0[j] = 0.f; accz1[j] = 0.f; }

        for (int kc = 0; kc < 128; kc += 16) {
            {
                int gn = min(node0 + snd, n - 1);
                float4 v = *(const float4*)&H[(size_t)gn * 128 + kc + sc4 * 4];
                sA[sc4 * 4 + 0][snd] = v.x;
                sA[sc4 * 4 + 1][snd] = v.y;
                sA[sc4 * 4 + 2][snd] = v.z;
                sA[sc4 * 4 + 3][snd] = v.w;
                if (t < 512) {
                    int idx = t & 255;
                    const float4* wsrc = (const float4*)(((t < 256) ? Wl : Wr) + (size_t)kc * 64);
                    float4* wdst = (float4*)((t < 256) ? &sWl[0][0] : &sWr[0][0]);
                    wdst[idx] = wsrc[idx];
                }
            }
            __syncthreads();
#pragma unroll
            for (int k = 0; k < 16; ++k) {
                float wlv[8], wrv[8];
                *(float4*)&wlv[0] = *(const float4*)&sWl[k][cg * 8];
                *(float4*)&wlv[4] = *(const float4*)&sWl[k][cg * 8 + 4];
                *(float4*)&wrv[0] = *(const float4*)&sWr[k][cg * 8];
                *(float4*)&wrv[4] = *(const float4*)&sWr[k][cg * 8 + 4];
                float a0 = sA[k][ln], a1 = sA[k][ln + 128];
#pragma unroll
                for (int j = 0; j < 8; ++j) {
                    accp0[j] += a0 * wlv[j];
                    accz0[j] += a0 * wrv[j];
                    accp1[j] += a1 * wlv[j];
                    accz1[j] += a1 * wrv[j];
                }
            }
            __syncthreads();
        }
        int n0 = node0 + ln, n1 = node0 + ln + 128;
        if (n0 < n) {
            *(float4*)&p[(size_t)n0 * 64 + cg * 8]     = *(float4*)&accp0[0];
            *(float4*)&p[(size_t)n0 * 64 + cg * 8 + 4] = *(float4*)&accp0[4];
            float4 v0, v1;
            float* q0 = &v0.x; float* q1 = &v1.x;
#pragma unroll
            for (int j = 0; j < 4; ++j) { q0[j] = accz0[j] + bs[j]; q1[j] = accz0[j + 4] + bs[j + 4]; }
            *(float4*)&z[(size_t)n0 * 64 + cg * 8]     = v0;
            *(float4*)&z[(size_t)n0 * 64 + cg * 8 + 4] = v1;
        }
        if (n1 < n) {
            *(float4*)&p[(size_t)n1 * 64 + cg * 8]     = *(float4*)&accp1[0];
            *(float4*)&p[(size_t)n1 * 64 + cg * 8 + 4] = *(float4*)&accp1[4];
            float4 v0, v1;
            float* q0 = &v0.x; float* q1 = &v1.x;
#pragma unroll
            for (int j = 0; j < 4; ++j) { q0[j] = accz1[j] + bs[j]; q1[j] = accz1[j + 4] + bs[j + 4]; }
            *(float4*)&z[(size_t)n1 * 64 + cg * 8]     = v0;
            *(float4*)&z[(size_t)n1 * 64 + cg * 8 + 4] = v1;
        }
    }
}

// ---------------- launch ----------------

extern "C" void kernel_launch(void* const* d_in, const int* in_sizes, int n_in,
                              void* d_out, int out_size, void* d_ws, size_t ws_size,
                              hipStream_t stream) {
    const float* x   = (const float*)d_in[0];
    const int*   ei  = (const int*)d_in[1];
    const float* Wl1 = (const float*)d_in[2];
    const float* Wr1 = (const float*)d_in[3];
    const float* b1  = (const float*)d_in[4];
    const float* Wl2 = (const float*)d_in[5];
    const float* Wr2 = (const float*)d_in[6];
    const float* b2  = (const float*)d_in[7];
    float* out = (float*)d_out;

    int Nn = in_sizes[0] / 128;
    int E  = in_sizes[1] / 2;
    const int* src = ei;
    const int* dst = ei + E;

    char* ws = (char*)d_ws;
    auto alloc = [&](size_t bytes) -> char* {
        char* p = ws;
        ws += (bytes + 255) / 256 * 256;
        return p;
    };
    int* deg       = (int*)alloc((size_t)Nn * 4);
    int* start     = (int*)alloc((size_t)Nn * 4);
    int* cursor    = (int*)alloc((size_t)Nn * 4);
    int* partial   = (int*)alloc((size_t)Nn * 4);
    int* blockSums = (int*)alloc(4096);
    int* csr       = (int*)alloc((size_t)E * 4);
    float* agg1    = (float*)alloc((size_t)Nn * 128 * 4);
    float* h       = (float*)alloc((size_t)Nn * 128 * 4);
    float* p       = (float*)alloc((size_t)Nn * 64 * 4);

    hipMemsetAsync(deg, 0, (size_t)Nn * 4, stream);

    int nb = (Nn + 255) / 256;  // 391 <= 512
    k_deg<<<(E + 255) / 256, 256, 0, stream>>>(dst, deg, E);
    k_scan1<<<nb, 256, 0, stream>>>(deg, partial, blockSums, Nn);
    k_scan2<<<1, 512, 0, stream>>>(blockSums, nb);
    k_scan3<<<nb, 256, 0, stream>>>(partial, blockSums, start, cursor, Nn);
    k_scatter<<<(E + 255) / 256, 256, 0, stream>>>(src, dst, cursor, csr, E);

    // layer 1: agg1 = mean-agg(x); h = relu(agg1@Wl1 + x@Wr1 + b1)
    agg_l1<<<(Nn + 3) / 4, 256, 0, stream>>>(x, csr, start, deg, agg1, Nn);
    int nt1 = (Nn + 127) / 128;
    gemm_l1<<<256, 1024, 0, stream>>>(agg1, x, Wl1, Wr1, b1, h, Nn, nt1);

    // layer 2 (linearity): p = h@Wl2; out = h@Wr2 + b2; then out += mean-agg(p)
    int nt2 = (Nn + 255) / 256;
    gemm_l2<<<256, 1024, 0, stream>>>(h, Wl2, Wr2, b2, p, out, Nn, nt2);
    agg_l2<<<(Nn + 3) / 4, 256, 0, stream>>>(p, csr, start, deg, out, Nn);
}

// Round 3
// 1443.334 us; speedup vs baseline: 2.5507x; 2.5507x over previous
//
#include <hip/hip_runtime.h>

// ---------------- CSR build ----------------

__global__ void k_deg(const int* __restrict__ dst, int* __restrict__ deg, int E) {
    int e = blockIdx.x * blockDim.x + threadIdx.x;
    if (e < E) atomicAdd(&deg[dst[e]], 1);
}

__global__ void k_scan1(const int* __restrict__ deg, int* __restrict__ partial,
                        int* __restrict__ blockSums, int n) {
    __shared__ int sh[256];
    int i = blockIdx.x * 256 + threadIdx.x;
    int v = (i < n) ? deg[i] : 0;
    sh[threadIdx.x] = v;
    __syncthreads();
    for (int off = 1; off < 256; off <<= 1) {
        int t = (threadIdx.x >= (unsigned)off) ? sh[threadIdx.x - off] : 0;
        __syncthreads();
        sh[threadIdx.x] += t;
        __syncthreads();
    }
    if (i < n) partial[i] = sh[threadIdx.x] - v;
    if (threadIdx.x == 255) blockSums[blockIdx.x] = sh[255];
}

__global__ void k_scan2(int* __restrict__ bs, int nb) {
    __shared__ int sh[512];
    int t = threadIdx.x;
    int v = (t < nb) ? bs[t] : 0;
    sh[t] = v;
    __syncthreads();
    for (int off = 1; off < 512; off <<= 1) {
        int u = (t >= off) ? sh[t - off] : 0;
        __syncthreads();
        sh[t] += u;
        __syncthreads();
    }
    if (t < nb) bs[t] = sh[t] - v;
}

__global__ void k_scan3(const int* __restrict__ partial, const int* __restrict__ bs,
                        int* __restrict__ start, int* __restrict__ cursor, int n) {
    int i = blockIdx.x * 256 + threadIdx.x;
    if (i < n) {
        int s = partial[i] + bs[blockIdx.x];
        start[i] = s;
        cursor[i] = s;
    }
}

__global__ void k_scatter(const int* __restrict__ src, const int* __restrict__ dst,
                          int* __restrict__ cursor, int* __restrict__ csr, int E) {
    int e = blockIdx.x * blockDim.x + threadIdx.x;
    if (e < E) {
        int d = dst[e];
        int p = atomicAdd(&cursor[d], 1);
        csr[p] = src[e];
    }
}

// ---------------- aggregation ----------------

__global__ void agg_l1(const float* __restrict__ feat, const int* __restrict__ csr,
                       const int* __restrict__ start, const int* __restrict__ deg,
                       float* __restrict__ agg, int n) {
    int gid = blockIdx.x * blockDim.x + threadIdx.x;
    int node = gid >> 6, lane = gid & 63;
    if (node >= n) return;
    int s = start[node], d = deg[node];
    const float2* f2 = (const float2*)feat;
    float2 a0 = {0.f, 0.f}, a1 = {0.f, 0.f}, a2 = {0.f, 0.f}, a3 = {0.f, 0.f};
    int j = 0;
    for (; j + 4 <= d; j += 4) {
        int i0 = csr[s + j], i1 = csr[s + j + 1], i2 = csr[s + j + 2], i3 = csr[s + j + 3];
        float2 v0 = f2[(size_t)i0 * 64 + lane];
        float2 v1 = f2[(size_t)i1 * 64 + lane];
        float2 v2 = f2[(size_t)i2 * 64 + lane];
        float2 v3 = f2[(size_t)i3 * 64 + lane];
        a0.x += v0.x; a0.y += v0.y;
        a1.x += v1.x; a1.y += v1.y;
        a2.x += v2.x; a2.y += v2.y;
        a3.x += v3.x; a3.y += v3.y;
    }
    for (; j < d; ++j) {
        float2 v = f2[(size_t)csr[s + j] * 64 + lane];
        a0.x += v.x; a0.y += v.y;
    }
    float inv = 1.0f / (float)max(d, 1);
    float2 r;
    r.x = ((a0.x + a1.x) + (a2.x + a3.x)) * inv;
    r.y = ((a0.y + a1.y) + (a2.y + a3.y)) * inv;
    ((float2*)agg)[(size_t)node * 64 + lane] = r;
}

__global__ void agg_l2(const float* __restrict__ p, const int* __restrict__ csr,
                       const int* __restrict__ start, const int* __restrict__ deg,
                       float* __restrict__ out, int n) {
    int gid = blockIdx.x * blockDim.x + threadIdx.x;
    int node = gid >> 6, lane = gid & 63;
    if (node >= n) return;
    int s = start[node], d = deg[node];
    float a0 = 0.f, a1 = 0.f, a2 = 0.f, a3 = 0.f;
    int j = 0;
    for (; j + 4 <= d; j += 4) {
        int i0 = csr[s + j], i1 = csr[s + j + 1], i2 = csr[s + j + 2], i3 = csr[s + j + 3];
        a0 += p[(size_t)i0 * 64 + lane];
        a1 += p[(size_t)i1 * 64 + lane];
        a2 += p[(size_t)i2 * 64 + lane];
        a3 += p[(size_t)i3 * 64 + lane];
    }
    for (; j < d; ++j) a0 += p[(size_t)csr[s + j] * 64 + lane];
    float m = (a0 + a1) + (a2 + a3);
    size_t o = (size_t)node * 64 + lane;
    out[o] = out[o] + m / (float)max(d, 1);
}

// ---------------- layer-1 dual GEMM: h = relu(A@Wl + B@Wr + b) ----------------
// 256 threads, tile 64 nodes x 128 cols, KC=16. Thread = 2 nodes x 16 cols (32 acc).
// launch_bounds(256,2): VGPR cap 256 -> no spills (round-2 killer).

__global__ __launch_bounds__(256, 2) void gemm_l1(
    const float* __restrict__ A, const float* __restrict__ B,
    const float* __restrict__ Wl, const float* __restrict__ Wr,
    const float* __restrict__ bias, float* __restrict__ out, int n) {
    __shared__ float sA[16][66];
    __shared__ float sB[16][66];
    __shared__ float sWl[16][128];
    __shared__ float sWr[16][128];
    int t = threadIdx.x;
    int ln = t & 31;   // nodes ln, ln+32
    int cg = t >> 5;   // 0..7 -> cols [cg*16, cg*16+16)
    int node0 = blockIdx.x * 64;

    int snd = t >> 2;  // staging node 0..63
    int sc4 = t & 3;   // staging float4 within K-chunk
    int gn = min(node0 + snd, n - 1);
    const float4* Arow = (const float4*)(A + (size_t)gn * 128);
    const float4* Brow = (const float4*)(B + (size_t)gn * 128);

    float acc0[16], acc1[16];
#pragma unroll
    for (int j = 0; j < 16; ++j) { acc0[j] = 0.f; acc1[j] = 0.f; }

    for (int kc = 0; kc < 128; kc += 16) {
        float4 va = Arow[(kc >> 2) + sc4];
        float4 vb = Brow[(kc >> 2) + sc4];
        sA[sc4 * 4 + 0][snd] = va.x;
        sA[sc4 * 4 + 1][snd] = va.y;
        sA[sc4 * 4 + 2][snd] = va.z;
        sA[sc4 * 4 + 3][snd] = va.w;
        sB[sc4 * 4 + 0][snd] = vb.x;
        sB[sc4 * 4 + 1][snd] = vb.y;
        sB[sc4 * 4 + 2][snd] = vb.z;
        sB[sc4 * 4 + 3][snd] = vb.w;
        const float4* wl4 = (const float4*)(Wl + (size_t)kc * 128);
        const float4* wr4 = (const float4*)(Wr + (size_t)kc * 128);
        float4* dl = (float4*)&sWl[0][0];
        float4* dr = (float4*)&sWr[0][0];
        dl[t] = wl4[t];
        dl[t + 256] = wl4[t + 256];
        dr[t] = wr4[t];
        dr[t + 256] = wr4[t + 256];
        __syncthreads();

#pragma unroll
        for (int k = 0; k < 16; ++k) {
            float a0 = sA[k][ln], a1 = sA[k][ln + 32];
            float b0 = sB[k][ln], b1 = sB[k][ln + 32];
#pragma unroll
            for (int j4 = 0; j4 < 4; ++j4) {
                float4 wl = *(const float4*)&sWl[k][cg * 16 + j4 * 4];
                float4 wr = *(const float4*)&sWr[k][cg * 16 + j4 * 4];
                acc0[j4 * 4 + 0] += a0 * wl.x + b0 * wr.x;
                acc0[j4 * 4 + 1] += a0 * wl.y + b0 * wr.y;
                acc0[j4 * 4 + 2] += a0 * wl.z + b0 * wr.z;
                acc0[j4 * 4 + 3] += a0 * wl.w + b0 * wr.w;
                acc1[j4 * 4 + 0] += a1 * wl.x + b1 * wr.x;
                acc1[j4 * 4 + 1] += a1 * wl.y + b1 * wr.y;
                acc1[j4 * 4 + 2] += a1 * wl.z + b1 * wr.z;
                acc1[j4 * 4 + 3] += a1 * wl.w + b1 * wr.w;
            }
        }
        __syncthreads();
    }

    int n0 = node0 + ln, n1 = node0 + ln + 32;
    if (n0 < n) {
#pragma unroll
        for (int j4 = 0; j4 < 4; ++j4) {
            float4 v;
            v.x = fmaxf(acc0[j4 * 4 + 0] + bias[cg * 16 + j4 * 4 + 0], 0.f);
            v.y = fmaxf(acc0[j4 * 4 + 1] + bias[cg * 16 + j4 * 4 + 1], 0.f);
            v.z = fmaxf(acc0[j4 * 4 + 2] + bias[cg * 16 + j4 * 4 + 2], 0.f);
            v.w = fmaxf(acc0[j4 * 4 + 3] + bias[cg * 16 + j4 * 4 + 3], 0.f);
            *(float4*)&out[(size_t)n0 * 128 + cg * 16 + j4 * 4] = v;
        }
    }
    if (n1 < n) {
#pragma unroll
        for (int j4 = 0; j4 < 4; ++j4) {
            float4 v;
            v.x = fmaxf(acc1[j4 * 4 + 0] + bias[cg * 16 + j4 * 4 + 0], 0.f);
            v.y = fmaxf(acc1[j4 * 4 + 1] + bias[cg * 16 + j4 * 4 + 1], 0.f);
            v.z = fmaxf(acc1[j4 * 4 + 2] + bias[cg * 16 + j4 * 4 + 2], 0.f);
            v.w = fmaxf(acc1[j4 * 4 + 3] + bias[cg * 16 + j4 * 4 + 3], 0.f);
            *(float4*)&out[(size_t)n1 * 128 + cg * 16 + j4 * 4] = v;
        }
    }
}

// ---------------- layer-2 dual-output GEMM: p = H@Wl2 ; z = H@Wr2 + b2 --------
// Concat output cols: c<64 -> p, c>=64 -> z. Tile 64 nodes x 128 cols, KC=16.

__global__ __launch_bounds__(256, 2) void gemm_l2(
    const float* __restrict__ H, const float* __restrict__ Wl,
    const float* __restrict__ Wr, const float* __restrict__ bias,
    float* __restrict__ p, float* __restrict__ z, int n) {
    __shared__ float sA[16][66];
    __shared__ float sW[16][128];  // [k][c]: c<64 from Wl, c>=64 from Wr
    int t = threadIdx.x;
    int ln = t & 31;
    int cg = t >> 5;   // 0..7; cg<4 -> p cols cg*16, cg>=4 -> z cols (cg-4)*16
    int node0 = blockIdx.x * 64;

    int snd = t >> 2;
    int sc4 = t & 3;
    int gn = min(node0 + snd, n - 1);
    const float4* Hrow = (const float4*)(H + (size_t)gn * 128);

    float acc0[16], acc1[16];
#pragma unroll
    for (int j = 0; j < 16; ++j) { acc0[j] = 0.f; acc1[j] = 0.f; }

    for (int kc = 0; kc < 128; kc += 16) {
        float4 va = Hrow[(kc >> 2) + sc4];
        sA[sc4 * 4 + 0][snd] = va.x;
        sA[sc4 * 4 + 1][snd] = va.y;
        sA[sc4 * 4 + 2][snd] = va.z;
        sA[sc4 * 4 + 3][snd] = va.w;
        {
            // sW: 16x128 floats = 512 float4; thread loads idx t and t+256.
#pragma unroll
            for (int u = 0; u < 2; ++u) {
                int idx = t + u * 256;
                int fk = (idx * 4) >> 7;        // k row 0..15
                int fc = (idx * 4) & 127;       // col 0..124 step 4
                const float* wsrc = (fc < 64) ? (Wl + (size_t)(kc + fk) * 64 + fc)
                                              : (Wr + (size_t)(kc + fk) * 64 + (fc - 64));
                *(float4*)&sW[fk][fc] = *(const float4*)wsrc;
            }
        }
        __syncthreads();

#pragma unroll
        for (int k = 0; k < 16; ++k) {
            float a0 = sA[k][ln], a1 = sA[k][ln + 32];
#pragma unroll
            for (int j4 = 0; j4 < 4; ++j4) {
                float4 w = *(const float4*)&sW[k][cg * 16 + j4 * 4];
                acc0[j4 * 4 + 0] += a0 * w.x;
                acc0[j4 * 4 + 1] += a0 * w.y;
                acc0[j4 * 4 + 2] += a0 * w.z;
                acc0[j4 * 4 + 3] += a0 * w.w;
                acc1[j4 * 4 + 0] += a1 * w.x;
                acc1[j4 * 4 + 1] += a1 * w.y;
                acc1[j4 * 4 + 2] += a1 * w.z;
                acc1[j4 * 4 + 3] += a1 * w.w;
            }
        }
        __syncthreads();
    }

    int n0 = node0 + ln, n1 = node0 + ln + 32;
    if (cg < 4) {
        int c0 = cg * 16;
        if (n0 < n) {
#pragma unroll
            for (int j4 = 0; j4 < 4; ++j4)
                *(float4*)&p[(size_t)n0 * 64 + c0 + j4 * 4] = *(float4*)&acc0[j4 * 4];
        }
        if (n1 < n) {
#pragma unroll
            for (int j4 = 0; j4 < 4; ++j4)
                *(float4*)&p[(size_t)n1 * 64 + c0 + j4 * 4] = *(float4*)&acc1[j4 * 4];
        }
    } else {
        int c0 = (cg - 4) * 16;
        if (n0 < n) {
#pragma unroll
            for (int j4 = 0; j4 < 4; ++j4) {
                float4 v;
                v.x = acc0[j4 * 4 + 0] + bias[c0 + j4 * 4 + 0];
                v.y = acc0[j4 * 4 + 1] + bias[c0 + j4 * 4 + 1];
                v.z = acc0[j4 * 4 + 2] + bias[c0 + j4 * 4 + 2];
                v.w = acc0[j4 * 4 + 3] + bias[c0 + j4 * 4 + 3];
                *(float4*)&z[(size_t)n0 * 64 + c0 + j4 * 4] = v;
            }
        }
        if (n1 < n) {
#pragma unroll
            for (int j4 = 0; j4 < 4; ++j4) {
                float4 v;
                v.x = acc1[j4 * 4 + 0] + bias[c0 + j4 * 4 + 0];
                v.y = acc1[j4 * 4 + 1] + bias[c0 + j4 * 4 + 1];
                v.z = acc1[j4 * 4 + 2] + bias[c0 + j4 * 4 + 2];
                v.w = acc1[j4 * 4 + 3] + bias[c0 + j4 * 4 + 3];
                *(float4*)&z[(size_t)n1 * 64 + c0 + j4 * 4] = v;
            }
        }
    }
}

// ---------------- launch ----------------

extern "C" void kernel_launch(void* const* d_in, const int* in_sizes, int n_in,
                              void* d_out, int out_size, void* d_ws, size_t ws_size,
                              hipStream_t stream) {
    const float* x   = (const float*)d_in[0];
    const int*   ei  = (const int*)d_in[1];
    const float* Wl1 = (const float*)d_in[2];
    const float* Wr1 = (const float*)d_in[3];
    const float* b1  = (const float*)d_in[4];
    const float* Wl2 = (const float*)d_in[5];
    const float* Wr2 = (const float*)d_in[6];
    const float* b2  = (const float*)d_in[7];
    float* out = (float*)d_out;

    int Nn = in_sizes[0] / 128;
    int E  = in_sizes[1] / 2;
    const int* src = ei;
    const int* dst = ei + E;

    char* ws = (char*)d_ws;
    auto alloc = [&](size_t bytes) -> char* {
        char* pp = ws;
        ws += (bytes + 255) / 256 * 256;
        return pp;
    };
    int* deg       = (int*)alloc((size_t)Nn * 4);
    int* start     = (int*)alloc((size_t)Nn * 4);
    int* cursor    = (int*)alloc((size_t)Nn * 4);
    int* partial   = (int*)alloc((size_t)Nn * 4);
    int* blockSums = (int*)alloc(4096);
    int* csr       = (int*)alloc((size_t)E * 4);
    float* agg1    = (float*)alloc((size_t)Nn * 128 * 4);
    float* h       = (float*)alloc((size_t)Nn * 128 * 4);
    float* p       = (float*)alloc((size_t)Nn * 64 * 4);

    hipMemsetAsync(deg, 0, (size_t)Nn * 4, stream);

    int nb = (Nn + 255) / 256;
    k_deg<<<(E + 255) / 256, 256, 0, stream>>>(dst, deg, E);
    k_scan1<<<nb, 256, 0, stream>>>(deg, partial, blockSums, Nn);
    k_scan2<<<1, 512, 0, stream>>>(blockSums, nb);
    k_scan3<<<nb, 256, 0, stream>>>(partial, blockSums, start, cursor, Nn);
    k_scatter<<<(E + 255) / 256, 256, 0, stream>>>(src, dst, cursor, csr, E);

    int ntiles = (Nn + 63) / 64;
    // layer 1
    agg_l1<<<(Nn + 3) / 4, 256, 0, stream>>>(x, csr, start, deg, agg1, Nn);
    gemm_l1<<<ntiles, 256, 0, stream>>>(agg1, x, Wl1, Wr1, b1, h, Nn);
    // layer 2 (linearity): p = h@Wl2; out = h@Wr2 + b2; out += mean-agg(p)
    gemm_l2<<<ntiles, 256, 0, stream>>>(h, Wl2, Wr2, b2, p, out, Nn);
    agg_l2<<<(Nn + 3) / 4, 256, 0, stream>>>(p, csr, start, deg, out, Nn);
}

// Round 4
// 560.569 us; speedup vs baseline: 6.5675x; 2.5748x over previous
//
#include <hip/hip_runtime.h>

typedef __attribute__((ext_vector_type(8))) short bf16x8;
typedef __attribute__((ext_vector_type(4))) float f32x4;

__device__ __forceinline__ f32x4 mfma16(bf16x8 a, bf16x8 b, f32x4 c) {
    return __builtin_amdgcn_mfma_f32_16x16x32_bf16(a, b, c, 0, 0, 0);
}

__device__ __forceinline__ unsigned short bf16_rte(float f) {
    unsigned int u = __float_as_uint(f);
    unsigned int r = (u + 0x7FFFu + ((u >> 16) & 1u)) >> 16;
    return (unsigned short)r;
}
__device__ __forceinline__ float bf16_f(unsigned short h) {
    return __uint_as_float(((unsigned int)h) << 16);
}

// ---------------- CSR build ----------------

__global__ void k_deg(const int* __restrict__ dst, int* __restrict__ deg, int E) {
    int e = blockIdx.x * blockDim.x + threadIdx.x;
    if (e < E) atomicAdd(&deg[dst[e]], 1);
}

__global__ void k_scan1(const int* __restrict__ deg, int* __restrict__ partial,
                        int* __restrict__ blockSums, int n) {
    __shared__ int sh[256];
    int i = blockIdx.x * 256 + threadIdx.x;
    int v = (i < n) ? deg[i] : 0;
    sh[threadIdx.x] = v;
    __syncthreads();
    for (int off = 1; off < 256; off <<= 1) {
        int t = (threadIdx.x >= (unsigned)off) ? sh[threadIdx.x - off] : 0;
        __syncthreads();
        sh[threadIdx.x] += t;
        __syncthreads();
    }
    if (i < n) partial[i] = sh[threadIdx.x] - v;
    if (threadIdx.x == 255) blockSums[blockIdx.x] = sh[255];
}

__global__ void k_scan2(int* __restrict__ bs, int nb) {
    __shared__ int sh[512];
    int t = threadIdx.x;
    int v = (t < nb) ? bs[t] : 0;
    sh[t] = v;
    __syncthreads();
    for (int off = 1; off < 512; off <<= 1) {
        int u = (t >= off) ? sh[t - off] : 0;
        __syncthreads();
        sh[t] += u;
        __syncthreads();
    }
    if (t < nb) bs[t] = sh[t] - v;
}

__global__ void k_scan3(const int* __restrict__ partial, const int* __restrict__ bs,
                        int* __restrict__ start, int* __restrict__ cursor, int n) {
    int i = blockIdx.x * 256 + threadIdx.x;
    if (i < n) {
        int s = partial[i] + bs[blockIdx.x];
        start[i] = s;
        cursor[i] = s;
    }
}

__global__ void k_scatter(const int* __restrict__ src, const int* __restrict__ dst,
                          int* __restrict__ cursor, int* __restrict__ csr, int E) {
    int e = blockIdx.x * blockDim.x + threadIdx.x;
    if (e < E) {
        int d = dst[e];
        int p = atomicAdd(&cursor[d], 1);
        csr[p] = src[e];
    }
}

// ---------------- aggregation (unchanged) ----------------

__global__ void agg_l1(const float* __restrict__ feat, const int* __restrict__ csr,
                       const int* __restrict__ start, const int* __restrict__ deg,
                       float* __restrict__ agg, int n) {
    int gid = blockIdx.x * blockDim.x + threadIdx.x;
    int node = gid >> 6, lane = gid & 63;
    if (node >= n) return;
    int s = start[node], d = deg[node];
    const float2* f2 = (const float2*)feat;
    float2 a0 = {0.f, 0.f}, a1 = {0.f, 0.f}, a2 = {0.f, 0.f}, a3 = {0.f, 0.f};
    int j = 0;
    for (; j + 4 <= d; j += 4) {
        int i0 = csr[s + j], i1 = csr[s + j + 1], i2 = csr[s + j + 2], i3 = csr[s + j + 3];
        float2 v0 = f2[(size_t)i0 * 64 + lane];
        float2 v1 = f2[(size_t)i1 * 64 + lane];
        float2 v2 = f2[(size_t)i2 * 64 + lane];
        float2 v3 = f2[(size_t)i3 * 64 + lane];
        a0.x += v0.x; a0.y += v0.y;
        a1.x += v1.x; a1.y += v1.y;
        a2.x += v2.x; a2.y += v2.y;
        a3.x += v3.x; a3.y += v3.y;
    }
    for (; j < d; ++j) {
        float2 v = f2[(size_t)csr[s + j] * 64 + lane];
        a0.x += v.x; a0.y += v.y;
    }
    float inv = 1.0f / (float)max(d, 1);
    float2 r;
    r.x = ((a0.x + a1.x) + (a2.x + a3.x)) * inv;
    r.y = ((a0.y + a1.y) + (a2.y + a3.y)) * inv;
    ((float2*)agg)[(size_t)node * 64 + lane] = r;
}

__global__ void agg_l2(const float* __restrict__ p, const int* __restrict__ csr,
                       const int* __restrict__ start, const int* __restrict__ deg,
                       float* __restrict__ out, int n) {
    int gid = blockIdx.x * blockDim.x + threadIdx.x;
    int node = gid >> 6, lane = gid & 63;
    if (node >= n) return;
    int s = start[node], d = deg[node];
    float a0 = 0.f, a1 = 0.f, a2 = 0.f, a3 = 0.f;
    int j = 0;
    for (; j + 4 <= d; j += 4) {
        int i0 = csr[s + j], i1 = csr[s + j + 1], i2 = csr[s + j + 2], i3 = csr[s + j + 3];
        a0 += p[(size_t)i0 * 64 + lane];
        a1 += p[(size_t)i1 * 64 + lane];
        a2 += p[(size_t)i2 * 64 + lane];
        a3 += p[(size_t)i3 * 64 + lane];
    }
    for (; j < d; ++j) a0 += p[(size_t)csr[s + j] * 64 + lane];
    float m = (a0 + a1) + (a2 + a3);
    size_t o = (size_t)node * 64 + lane;
    out[o] = out[o] + m / (float)max(d, 1);
}

// ---------------- MFMA GEMM (bf16x3 split = fp32 accuracy) ----------------
// Block: 256 thr = 4 waves; tile 128 nodes x 64 cols; wave = 64 nodes x 32 cols
// = 4 node-tiles x 2 col-tiles of 16x16x32 MFMA. K staged in chunks of 32.
// LDS: A hi/lo [128][40] ushorts + W^T hi/lo [64][40] = 30.7 KB.
// Frag layouts (HW-verified, m89/m120): A[m=lane&15][k=(lane>>4)*8+j];
// B from W^T[col][k] same pattern; D col=lane&15, row=(lane>>4)*4+reg.

#define SR 40  // LDS row stride in ushorts (80 B: 16B-aligned, 2-way-only banks)

// layer 1: h = relu([agg1|x](K=256) @ [Wl1;Wr1] + b1)
__global__ __launch_bounds__(256, 2) void mfma_l1(
    const float* __restrict__ AggA, const float* __restrict__ X,
    const float* __restrict__ Wl, const float* __restrict__ Wr,
    const float* __restrict__ bias, float* __restrict__ h, int n) {
    __shared__ unsigned short aHi[128 * SR], aLo[128 * SR];
    __shared__ unsigned short wHi[64 * SR], wLo[64 * SR];

    int t = threadIdx.x;
    int wv = t >> 6, l = t & 63, q = l >> 4, nl = l & 15;
    int wn = (wv & 1) * 64, wc = (wv >> 1) * 32;
    int node0 = blockIdx.x * 128;
    int col0 = blockIdx.y * 64;

    int sn = t >> 1, sh = t & 1;                 // A staging: node, k-half
    int gn = min(node0 + sn, n - 1);

    f32x4 acc[4][2];
#pragma unroll
    for (int a = 0; a < 4; ++a)
#pragma unroll
        for (int b = 0; b < 2; ++b) acc[a][b] = (f32x4){0.f, 0.f, 0.f, 0.f};

    for (int c = 0; c < 8; ++c) {
        int ksrc = c * 32;
        const float* Asrc = (ksrc < 128) ? AggA : X;
        const float* Wsrc = (ksrc < 128) ? (Wl + (size_t)ksrc * 128)
                                         : (Wr + (size_t)(ksrc - 128) * 128);
        int ka = ksrc & 127;
        // stage A: 128 nodes x 32 k
        {
            const float4* ap = (const float4*)(Asrc + (size_t)gn * 128 + ka);
#pragma unroll
            for (int i = 0; i < 4; ++i) {
                float4 v = ap[sh * 4 + i];
                int base = sn * SR + sh * 16 + i * 4;
                ushort4 hi, lo;
                hi.x = bf16_rte(v.x); lo.x = bf16_rte(v.x - bf16_f(hi.x));
                hi.y = bf16_rte(v.y); lo.y = bf16_rte(v.y - bf16_f(hi.y));
                hi.z = bf16_rte(v.z); lo.z = bf16_rte(v.z - bf16_f(hi.z));
                hi.w = bf16_rte(v.w); lo.w = bf16_rte(v.w - bf16_f(hi.w));
                *(ushort4*)&aHi[base] = hi;
                *(ushort4*)&aLo[base] = lo;
            }
        }
        // stage W^T: 32 k x 64 cols -> [col][k]
        {
#pragma unroll
            for (int rep = 0; rep < 2; ++rep) {
                int idx = t + rep * 256;
                int fk = idx >> 4, fc = (idx & 15) * 4;
                float4 v = *(const float4*)(Wsrc + (size_t)fk * 128 + col0 + fc);
                const float* vp = &v.x;
#pragma unroll
                for (int s = 0; s < 4; ++s) {
                    unsigned short hi = bf16_rte(vp[s]);
                    wHi[(fc + s) * SR + fk] = hi;
                    wLo[(fc + s) * SR + fk] = bf16_rte(vp[s] - bf16_f(hi));
                }
            }
        }
        __syncthreads();

        bf16x8 ah[4], al[4], wh[2], wl2[2];
#pragma unroll
        for (int tt = 0; tt < 4; ++tt) {
            int off = (wn + tt * 16 + nl) * SR + q * 8;
            ah[tt] = *(const bf16x8*)&aHi[off];
            al[tt] = *(const bf16x8*)&aLo[off];
        }
#pragma unroll
        for (int uu = 0; uu < 2; ++uu) {
            int off = (wc + uu * 16 + nl) * SR + q * 8;
            wh[uu] = *(const bf16x8*)&wHi[off];
            wl2[uu] = *(const bf16x8*)&wLo[off];
        }
#pragma unroll
        for (int tt = 0; tt < 4; ++tt)
#pragma unroll
            for (int uu = 0; uu < 2; ++uu) {
                f32x4 a = acc[tt][uu];
                a = mfma16(al[tt], wh[uu], a);
                a = mfma16(ah[tt], wl2[uu], a);
                a = mfma16(ah[tt], wh[uu], a);
                acc[tt][uu] = a;
            }
        __syncthreads();
    }

#pragma unroll
    for (int uu = 0; uu < 2; ++uu) {
        int col = col0 + wc + uu * 16 + nl;
        float bv = bias[col];
#pragma unroll
        for (int tt = 0; tt < 4; ++tt) {
#pragma unroll
            for (int r = 0; r < 4; ++r) {
                int node = node0 + wn + tt * 16 + q * 4 + r;
                if (node < n)
                    h[(size_t)node * 128 + col] = fmaxf(acc[tt][uu][r] + bv, 0.f);
            }
        }
    }
}

// layer 2: y=0: p = H@Wl2 ; y=1: out = H@Wr2 + b2.  K=128, 64 out cols.
__global__ __launch_bounds__(256, 2) void mfma_l2(
    const float* __restrict__ H, const float* __restrict__ Wl,
    const float* __restrict__ Wr, const float* __restrict__ bias,
    float* __restrict__ p, float* __restrict__ z, int n) {
    __shared__ unsigned short aHi[128 * SR], aLo[128 * SR];
    __shared__ unsigned short wHi[64 * SR], wLo[64 * SR];

    int t = threadIdx.x;
    int wv = t >> 6, l = t & 63, q = l >> 4, nl = l & 15;
    int wn = (wv & 1) * 64, wc = (wv >> 1) * 32;
    int node0 = blockIdx.x * 128;
    int ysel = blockIdx.y;
    const float* Wsrc0 = ysel ? Wr : Wl;
    float* dst = ysel ? z : p;

    int sn = t >> 1, sh = t & 1;
    int gn = min(node0 + sn, n - 1);

    f32x4 acc[4][2];
#pragma unroll
    for (int a = 0; a < 4; ++a)
#pragma unroll
        for (int b = 0; b < 2; ++b) acc[a][b] = (f32x4){0.f, 0.f, 0.f, 0.f};

    for (int c = 0; c < 4; ++c) {
        int ksrc = c * 32;
        {
            const float4* ap = (const float4*)(H + (size_t)gn * 128 + ksrc);
#pragma unroll
            for (int i = 0; i < 4; ++i) {
                float4 v = ap[sh * 4 + i];
                int base = sn * SR + sh * 16 + i * 4;
                ushort4 hi, lo;
                hi.x = bf16_rte(v.x); lo.x = bf16_rte(v.x - bf16_f(hi.x));
                hi.y = bf16_rte(v.y); lo.y = bf16_rte(v.y - bf16_f(hi.y));
                hi.z = bf16_rte(v.z); lo.z = bf16_rte(v.z - bf16_f(hi.z));
                hi.w = bf16_rte(v.w); lo.w = bf16_rte(v.w - bf16_f(hi.w));
                *(ushort4*)&aHi[base] = hi;
                *(ushort4*)&aLo[base] = lo;
            }
        }
        {
#pragma unroll
            for (int rep = 0; rep < 2; ++rep) {
                int idx = t + rep * 256;
                int fk = idx >> 4, fc = (idx & 15) * 4;
                float4 v = *(const float4*)(Wsrc0 + (size_t)(ksrc + fk) * 64 + fc);
                const float* vp = &v.x;
#pragma unroll
                for (int s = 0; s < 4; ++s) {
                    unsigned short hi = bf16_rte(vp[s]);
                    wHi[(fc + s) * SR + fk] = hi;
                    wLo[(fc + s) * SR + fk] = bf16_rte(vp[s] - bf16_f(hi));
                }
            }
        }
        __syncthreads();

        bf16x8 ah[4], al[4], wh[2], wl2[2];
#pragma unroll
        for (int tt = 0; tt < 4; ++tt) {
            int off = (wn + tt * 16 + nl) * SR + q * 8;
            ah[tt] = *(const bf16x8*)&aHi[off];
            al[tt] = *(const bf16x8*)&aLo[off];
        }
#pragma unroll
        for (int uu = 0; uu < 2; ++uu) {
            int off = (wc + uu * 16 + nl) * SR + q * 8;
            wh[uu] = *(const bf16x8*)&wHi[off];
            wl2[uu] = *(const bf16x8*)&wLo[off];
        }
#pragma unroll
        for (int tt = 0; tt < 4; ++tt)
#pragma unroll
            for (int uu = 0; uu < 2; ++uu) {
                f32x4 a = acc[tt][uu];
                a = mfma16(al[tt], wh[uu], a);
                a = mfma16(ah[tt], wl2[uu], a);
                a = mfma16(ah[tt], wh[uu], a);
                acc[tt][uu] = a;
            }
        __syncthreads();
    }

#pragma unroll
    for (int uu = 0; uu < 2; ++uu) {
        int col = wc + uu * 16 + nl;
        float bv = ysel ? bias[col] : 0.f;
#pragma unroll
        for (int tt = 0; tt < 4; ++tt) {
#pragma unroll
            for (int r = 0; r < 4; ++r) {
                int node = node0 + wn + tt * 16 + q * 4 + r;
                if (node < n)
                    dst[(size_t)node * 64 + col] = acc[tt][uu][r] + bv;
            }
        }
    }
}

// ---------------- launch ----------------

extern "C" void kernel_launch(void* const* d_in, const int* in_sizes, int n_in,
                              void* d_out, int out_size, void* d_ws, size_t ws_size,
                              hipStream_t stream) {
    const float* x   = (const float*)d_in[0];
    const int*   ei  = (const int*)d_in[1];
    const float* Wl1 = (const float*)d_in[2];
    const float* Wr1 = (const float*)d_in[3];
    const float* b1  = (const float*)d_in[4];
    const float* Wl2 = (const float*)d_in[5];
    const float* Wr2 = (const float*)d_in[6];
    const float* b2  = (const float*)d_in[7];
    float* out = (float*)d_out;

    int Nn = in_sizes[0] / 128;
    int E  = in_sizes[1] / 2;
    const int* src = ei;
    const int* dst = ei + E;

    char* ws = (char*)d_ws;
    auto alloc = [&](size_t bytes) -> char* {
        char* pp = ws;
        ws += (bytes + 255) / 256 * 256;
        return pp;
    };
    int* deg       = (int*)alloc((size_t)Nn * 4);
    int* start     = (int*)alloc((size_t)Nn * 4);
    int* cursor    = (int*)alloc((size_t)Nn * 4);
    int* partial   = (int*)alloc((size_t)Nn * 4);
    int* blockSums = (int*)alloc(4096);
    int* csr       = (int*)alloc((size_t)E * 4);
    float* agg1    = (float*)alloc((size_t)Nn * 128 * 4);
    float* h       = (float*)alloc((size_t)Nn * 128 * 4);
    float* p       = (float*)alloc((size_t)Nn * 64 * 4);

    hipMemsetAsync(deg, 0, (size_t)Nn * 4, stream);

    int nb = (Nn + 255) / 256;
    k_deg<<<(E + 255) / 256, 256, 0, stream>>>(dst, deg, E);
    k_scan1<<<nb, 256, 0, stream>>>(deg, partial, blockSums, Nn);
    k_scan2<<<1, 512, 0, stream>>>(blockSums, nb);
    k_scan3<<<nb, 256, 0, stream>>>(partial, blockSums, start, cursor, Nn);
    k_scatter<<<(E + 255) / 256, 256, 0, stream>>>(src, dst, cursor, csr, E);

    dim3 gg((Nn + 127) / 128, 2);
    // layer 1
    agg_l1<<<(Nn + 3) / 4, 256, 0, stream>>>(x, csr, start, deg, agg1, Nn);
    mfma_l1<<<gg, 256, 0, stream>>>(agg1, x, Wl1, Wr1, b1, h, Nn);
    // layer 2 (linearity): p = h@Wl2; out = h@Wr2 + b2; out += mean-agg(p)
    mfma_l2<<<gg, 256, 0, stream>>>(h, Wl2, Wr2, b2, p, out, Nn);
    agg_l2<<<(Nn + 3) / 4, 256, 0, stream>>>(p, csr, start, deg, out, Nn);
}

// Round 5
// 549.607 us; speedup vs baseline: 6.6985x; 1.0199x over previous
//
#include <hip/hip_runtime.h>
#include <hip/hip_fp16.h>

typedef __attribute__((ext_vector_type(8))) short bf16x8;
typedef __attribute__((ext_vector_type(4))) float f32x4;

__device__ __forceinline__ f32x4 mfma16(bf16x8 a, bf16x8 b, f32x4 c) {
    return __builtin_amdgcn_mfma_f32_16x16x32_bf16(a, b, c, 0, 0, 0);
}

__device__ __forceinline__ unsigned short bf16_rte(float f) {
    unsigned int u = __float_as_uint(f);
    unsigned int r = (u + 0x7FFFu + ((u >> 16) & 1u)) >> 16;
    return (unsigned short)r;
}
__device__ __forceinline__ float bf16_f(unsigned short h) {
    return __uint_as_float(((unsigned int)h) << 16);
}

// ---------------- CSR build ----------------

__global__ void k_deg(const int* __restrict__ dst, int* __restrict__ deg, int E) {
    int e = blockIdx.x * blockDim.x + threadIdx.x;
    if (e < E) atomicAdd(&deg[dst[e]], 1);
}

__global__ void k_scan1(const int* __restrict__ deg, int* __restrict__ partial,
                        int* __restrict__ blockSums, int n) {
    __shared__ int sh[256];
    int i = blockIdx.x * 256 + threadIdx.x;
    int v = (i < n) ? deg[i] : 0;
    sh[threadIdx.x] = v;
    __syncthreads();
    for (int off = 1; off < 256; off <<= 1) {
        int t = (threadIdx.x >= (unsigned)off) ? sh[threadIdx.x - off] : 0;
        __syncthreads();
        sh[threadIdx.x] += t;
        __syncthreads();
    }
    if (i < n) partial[i] = sh[threadIdx.x] - v;
    if (threadIdx.x == 255) blockSums[blockIdx.x] = sh[255];
}

__global__ void k_scan2(int* __restrict__ bs, int nb) {
    __shared__ int sh[512];
    int t = threadIdx.x;
    int v = (t < nb) ? bs[t] : 0;
    sh[t] = v;
    __syncthreads();
    for (int off = 1; off < 512; off <<= 1) {
        int u = (t >= off) ? sh[t - off] : 0;
        __syncthreads();
        sh[t] += u;
        __syncthreads();
    }
    if (t < nb) bs[t] = sh[t] - v;
}

__global__ void k_scan3(const int* __restrict__ partial, const int* __restrict__ bs,
                        int* __restrict__ start, int* __restrict__ cursor, int n) {
    int i = blockIdx.x * 256 + threadIdx.x;
    if (i < n) {
        int s = partial[i] + bs[blockIdx.x];
        start[i] = s;
        cursor[i] = s;
    }
}

__global__ void k_scatter(const int* __restrict__ src, const int* __restrict__ dst,
                          int* __restrict__ cursor, int* __restrict__ csr, int E) {
    int e = blockIdx.x * blockDim.x + threadIdx.x;
    if (e < E) {
        int d = dst[e];
        int p = atomicAdd(&cursor[d], 1);
        csr[p] = src[e];
    }
}

// ---------------- MFMA dual GEMM (bf16x3 split = fp32-grade accuracy) --------
// ysel=0: dstH = X@WA (fp16);  ysel=1: dstF = X@WB + bias (fp32).
// Tile 128 nodes x FOUT cols, K=128 staged in 4 chunks of 32.
// Frag layouts HW-verified (m89): A[m=lane&15][k=(lane>>4)*8+j], B from W^T[col][k],
// D: col=lane&15, row=(lane>>4)*4+reg.

#define SR 40  // LDS row stride in ushorts (80 B: 16B-aligned, 2-way-only banks)

template <int FOUT>
__global__ __launch_bounds__(256, 2) void gemm_dual(
    const float* __restrict__ X, const float* __restrict__ WA,
    const float* __restrict__ WB, const float* __restrict__ bias,
    __half* __restrict__ dstH, float* __restrict__ dstF, int n) {
    constexpr int CT = FOUT / 32;  // col-tiles per wave
    __shared__ unsigned short aHi[128 * SR], aLo[128 * SR];
    __shared__ unsigned short wHi[FOUT * SR], wLo[FOUT * SR];

    int t = threadIdx.x;
    int wv = t >> 6, l = t & 63, q = l >> 4, nl = l & 15;
    int wn = (wv & 1) * 64, wc = (wv >> 1) * (FOUT / 2);
    int node0 = blockIdx.x * 128;
    int ysel = blockIdx.y;
    const float* W = ysel ? WB : WA;

    int sn = t >> 1, sh2 = t & 1;
    int gn = min(node0 + sn, n - 1);

    f32x4 acc[4][CT];
#pragma unroll
    for (int a = 0; a < 4; ++a)
#pragma unroll
        for (int b = 0; b < CT; ++b) acc[a][b] = (f32x4){0.f, 0.f, 0.f, 0.f};

    for (int c = 0; c < 4; ++c) {
        int k0 = c * 32;
        // stage A: 128 nodes x 32 k, hi/lo bf16 split
        {
            const float4* ap = (const float4*)(X + (size_t)gn * 128 + k0);
#pragma unroll
            for (int i = 0; i < 4; ++i) {
                float4 v = ap[sh2 * 4 + i];
                int base = sn * SR + sh2 * 16 + i * 4;
                ushort4 hi, lo;
                hi.x = bf16_rte(v.x); lo.x = bf16_rte(v.x - bf16_f(hi.x));
                hi.y = bf16_rte(v.y); lo.y = bf16_rte(v.y - bf16_f(hi.y));
                hi.z = bf16_rte(v.z); lo.z = bf16_rte(v.z - bf16_f(hi.z));
                hi.w = bf16_rte(v.w); lo.w = bf16_rte(v.w - bf16_f(hi.w));
                *(ushort4*)&aHi[base] = hi;
                *(ushort4*)&aLo[base] = lo;
            }
        }
        // stage W^T: 32 k x FOUT cols -> [col][k]
        {
#pragma unroll
            for (int rep = 0; rep < FOUT / 32; ++rep) {
                int idx = t + rep * 256;
                int fk = idx / (FOUT / 4);
                int fc = (idx % (FOUT / 4)) * 4;
                float4 v = *(const float4*)(W + (size_t)(k0 + fk) * FOUT + fc);
                const float* vp = &v.x;
#pragma unroll
                for (int s = 0; s < 4; ++s) {
                    unsigned short hi = bf16_rte(vp[s]);
                    wHi[(fc + s) * SR + fk] = hi;
                    wLo[(fc + s) * SR + fk] = bf16_rte(vp[s] - bf16_f(hi));
                }
            }
        }
        __syncthreads();

        bf16x8 ah[4], al[4], wh[CT], wl2[CT];
#pragma unroll
        for (int tt = 0; tt < 4; ++tt) {
            int off = (wn + tt * 16 + nl) * SR + q * 8;
            ah[tt] = *(const bf16x8*)&aHi[off];
            al[tt] = *(const bf16x8*)&aLo[off];
        }
#pragma unroll
        for (int uu = 0; uu < CT; ++uu) {
            int off = (wc + uu * 16 + nl) * SR + q * 8;
            wh[uu] = *(const bf16x8*)&wHi[off];
            wl2[uu] = *(const bf16x8*)&wLo[off];
        }
#pragma unroll
        for (int tt = 0; tt < 4; ++tt)
#pragma unroll
            for (int uu = 0; uu < CT; ++uu) {
                f32x4 a = acc[tt][uu];
                a = mfma16(al[tt], wh[uu], a);
                a = mfma16(ah[tt], wl2[uu], a);
                a = mfma16(ah[tt], wh[uu], a);
                acc[tt][uu] = a;
            }
        __syncthreads();
    }

#pragma unroll
    for (int uu = 0; uu < CT; ++uu) {
        int col = wc + uu * 16 + nl;
        if (ysel) {
            float bv = bias[col];
#pragma unroll
            for (int tt = 0; tt < 4; ++tt)
#pragma unroll
                for (int r = 0; r < 4; ++r) {
                    int node = node0 + wn + tt * 16 + q * 4 + r;
                    if (node < n) dstF[(size_t)node * FOUT + col] = acc[tt][uu][r] + bv;
                }
        } else {
#pragma unroll
            for (int tt = 0; tt < 4; ++tt)
#pragma unroll
                for (int r = 0; r < 4; ++r) {
                    int node = node0 + wn + tt * 16 + q * 4 + r;
                    if (node < n) dstH[(size_t)node * FOUT + col] = __float2half(acc[tt][uu][r]);
                }
        }
    }
}

// ---------------- fused aggregations ----------------

// h = relu(mean-gather(u fp16) + v); one wave per node, lane = 2 features (half2).
__global__ void agg1(const __half* __restrict__ u, const float* __restrict__ v,
                     const int* __restrict__ csr, const int* __restrict__ start,
                     const int* __restrict__ deg, float* __restrict__ h, int n) {
    int gid = blockIdx.x * blockDim.x + threadIdx.x;
    int node = gid >> 6, lane = gid & 63;
    if (node >= n) return;
    int s = start[node], d = deg[node];
    const __half2* u2 = (const __half2*)u;
    float ax0 = 0.f, ay0 = 0.f, ax1 = 0.f, ay1 = 0.f;
    float ax2 = 0.f, ay2 = 0.f, ax3 = 0.f, ay3 = 0.f;
    int j = 0;
    for (; j + 4 <= d; j += 4) {
        int i0 = csr[s + j], i1 = csr[s + j + 1], i2 = csr[s + j + 2], i3 = csr[s + j + 3];
        float2 v0 = __half22float2(u2[(size_t)i0 * 64 + lane]);
        float2 v1 = __half22float2(u2[(size_t)i1 * 64 + lane]);
        float2 v2 = __half22float2(u2[(size_t)i2 * 64 + lane]);
        float2 v3 = __half22float2(u2[(size_t)i3 * 64 + lane]);
        ax0 += v0.x; ay0 += v0.y;
        ax1 += v1.x; ay1 += v1.y;
        ax2 += v2.x; ay2 += v2.y;
        ax3 += v3.x; ay3 += v3.y;
    }
    for (; j < d; ++j) {
        float2 v0 = __half22float2(u2[(size_t)csr[s + j] * 64 + lane]);
        ax0 += v0.x; ay0 += v0.y;
    }
    float inv = 1.0f / (float)max(d, 1);
    float2 vv = ((const float2*)v)[(size_t)node * 64 + lane];
    float2 r;
    r.x = fmaxf(((ax0 + ax1) + (ax2 + ax3)) * inv + vv.x, 0.f);
    r.y = fmaxf(((ay0 + ay1) + (ay2 + ay3)) * inv + vv.y, 0.f);
    ((float2*)h)[(size_t)node * 64 + lane] = r;
}

// out += mean-gather(p fp16); one wave per node, lane = 1 feature.
__global__ void agg2(const __half* __restrict__ p, const int* __restrict__ csr,
                     const int* __restrict__ start, const int* __restrict__ deg,
                     float* __restrict__ out, int n) {
    int gid = blockIdx.x * blockDim.x + threadIdx.x;
    int node = gid >> 6, lane = gid & 63;
    if (node >= n) return;
    int s = start[node], d = deg[node];
    float a0 = 0.f, a1 = 0.f, a2 = 0.f, a3 = 0.f;
    int j = 0;
    for (; j + 4 <= d; j += 4) {
        int i0 = csr[s + j], i1 = csr[s + j + 1], i2 = csr[s + j + 2], i3 = csr[s + j + 3];
        a0 += __half2float(p[(size_t)i0 * 64 + lane]);
        a1 += __half2float(p[(size_t)i1 * 64 + lane]);
        a2 += __half2float(p[(size_t)i2 * 64 + lane]);
        a3 += __half2float(p[(size_t)i3 * 64 + lane]);
    }
    for (; j < d; ++j) a0 += __half2float(p[(size_t)csr[s + j] * 64 + lane]);
    float m = (a0 + a1) + (a2 + a3);
    size_t o = (size_t)node * 64 + lane;
    out[o] = out[o] + m / (float)max(d, 1);
}

// ---------------- launch ----------------

extern "C" void kernel_launch(void* const* d_in, const int* in_sizes, int n_in,
                              void* d_out, int out_size, void* d_ws, size_t ws_size,
                              hipStream_t stream) {
    const float* x   = (const float*)d_in[0];
    const int*   ei  = (const int*)d_in[1];
    const float* Wl1 = (const float*)d_in[2];
    const float* Wr1 = (const float*)d_in[3];
    const float* b1  = (const float*)d_in[4];
    const float* Wl2 = (const float*)d_in[5];
    const float* Wr2 = (const float*)d_in[6];
    const float* b2  = (const float*)d_in[7];
    float* out = (float*)d_out;

    int Nn = in_sizes[0] / 128;
    int E  = in_sizes[1] / 2;
    const int* src = ei;
    const int* dst = ei + E;

    char* ws = (char*)d_ws;
    auto alloc = [&](size_t bytes) -> char* {
        char* pp = ws;
        ws += (bytes + 255) / 256 * 256;
        return pp;
    };
    int* deg       = (int*)alloc((size_t)Nn * 4);
    int* start     = (int*)alloc((size_t)Nn * 4);
    int* cursor    = (int*)alloc((size_t)Nn * 4);
    int* partial   = (int*)alloc((size_t)Nn * 4);
    int* blockSums = (int*)alloc(4096);
    int* csr       = (int*)alloc((size_t)E * 4);
    __half* u      = (__half*)alloc((size_t)Nn * 128 * 2);
    float* v       = (float*)alloc((size_t)Nn * 128 * 4);
    float* h       = (float*)alloc((size_t)Nn * 128 * 4);
    __half* p      = (__half*)alloc((size_t)Nn * 64 * 2);

    hipMemsetAsync(deg, 0, (size_t)Nn * 4, stream);

    int nb = (Nn + 255) / 256;
    k_deg<<<(E + 255) / 256, 256, 0, stream>>>(dst, deg, E);
    k_scan1<<<nb, 256, 0, stream>>>(deg, partial, blockSums, Nn);
    k_scan2<<<1, 512, 0, stream>>>(blockSums, nb);
    k_scan3<<<nb, 256, 0, stream>>>(partial, blockSums, start, cursor, Nn);
    k_scatter<<<(E + 255) / 256, 256, 0, stream>>>(src, dst, cursor, csr, E);

    dim3 gg((Nn + 127) / 128, 2);
    // layer 1 (linearity): u = x@Wl1 (fp16), v = x@Wr1 + b1; h = relu(agg(u) + v)
    gemm_dual<128><<<gg, 256, 0, stream>>>(x, Wl1, Wr1, b1, u, v, Nn);
    agg1<<<(Nn + 3) / 4, 256, 0, stream>>>(u, v, csr, start, deg, h, Nn);
    // layer 2 (linearity): p = h@Wl2 (fp16), out = h@Wr2 + b2; out += agg(p)
    gemm_dual<64><<<gg, 256, 0, stream>>>(h, Wl2, Wr2, b2, p, out, Nn);
    agg2<<<(Nn + 3) / 4, 256, 0, stream>>>(p, csr, start, deg, out, Nn);
}